// Round 3
// baseline (4232.550 us; speedup 1.0000x reference)
//
#include <hip/hip_runtime.h>

#define NUu 100000
#define NIi 100000
#define NAa 10000
#define DD  64
#define NN0 (NUu + NIi)   // 200000
#define NN1 (NUu + NAa)   // 110000
#define BKS 6             // 64 rows per bucket

// ---------------- CSR build kernels ----------------

__global__ void k_hist(const int* __restrict__ row, int* __restrict__ cnt, int E) {
    int e = blockIdx.x * blockDim.x + threadIdx.x;
    if (e >= E) return;
    atomicAdd(cnt + row[e], 1);
}

// per-block exclusive scan (256 elems/block), block sums out
__global__ void k_scan1(const int* __restrict__ cnt, int n,
                        int* __restrict__ excl, int* __restrict__ bsum) {
    __shared__ int s[256];
    int gid = blockIdx.x * 256 + threadIdx.x;
    int v = (gid < n) ? cnt[gid] : 0;
    s[threadIdx.x] = v;
    __syncthreads();
    for (int off = 1; off < 256; off <<= 1) {
        int t = (threadIdx.x >= off) ? s[threadIdx.x - off] : 0;
        __syncthreads();
        s[threadIdx.x] += t;
        __syncthreads();
    }
    if (gid < n) excl[gid] = s[threadIdx.x] - v;
    if (threadIdx.x == 255) bsum[blockIdx.x] = s[255];
}

// single-block exclusive scan of block sums (nb <= 1024)
__global__ void k_scan2(int* __restrict__ bsum, int nb) {
    __shared__ int s[1024];
    int v = (threadIdx.x < nb) ? bsum[threadIdx.x] : 0;
    s[threadIdx.x] = v;
    __syncthreads();
    for (int off = 1; off < 1024; off <<= 1) {
        int t = (threadIdx.x >= off) ? s[threadIdx.x - off] : 0;
        __syncthreads();
        s[threadIdx.x] += t;
        __syncthreads();
    }
    if (threadIdx.x < nb) bsum[threadIdx.x] = s[threadIdx.x] - v;
}

// combine -> row_ptr; rp[n] = E
__global__ void k_scan3(const int* __restrict__ excl, const int* __restrict__ bsum,
                        int n, int E, int* __restrict__ rp) {
    int gid = blockIdx.x * 256 + threadIdx.x;
    if (gid < n) rp[gid] = excl[gid] + bsum[gid >> 8];
    if (gid == n) rp[n] = E;
}

// bucket cursors = rp[b<<BKS]
__global__ void k_bktinit(const int* __restrict__ rp, int* __restrict__ bktCur, int nbkt) {
    int b = blockIdx.x * blockDim.x + threadIdx.x;
    if (b < nbkt) bktCur[b] = rp[b << BKS];
}

// phase A: append edges into per-bucket staging segments (quasi-sequential writes)
__global__ void k_scatter1(const int* __restrict__ row, const int* __restrict__ col,
                           const float* __restrict__ val, int* __restrict__ bktCur,
                           int* __restrict__ stageR, int2* __restrict__ stageP, int E) {
    int e = blockIdx.x * blockDim.x + threadIdx.x;
    if (e >= E) return;
    int r = row[e];
    int pos = atomicAdd(bktCur + (r >> BKS), 1);
    stageR[pos] = r;
    int2 p;
    p.x = col[e];
    p.y = __float_as_int(val[e]);
    stageP[pos] = p;
}

// phase B: one block per bucket; LDS cursors; writes confined to ~16KB window
__global__ void k_scatter2(const int* __restrict__ rp, const int* __restrict__ stageR,
                           const int2* __restrict__ stageP, int2* __restrict__ spair,
                           int N) {
    __shared__ int scur[1 << BKS];
    int base = blockIdx.x << BKS;
    int nr = min(1 << BKS, N - base);
    if (threadIdx.x < (1 << BKS))
        scur[threadIdx.x] = (threadIdx.x < nr) ? rp[base + threadIdx.x] : 0;
    __syncthreads();
    int es = rp[base];
    int ee = rp[base + nr];
    for (int i = es + threadIdx.x; i < ee; i += blockDim.x) {
        int r = stageR[i];
        int pos = atomicAdd(&scur[r & ((1 << BKS) - 1)], 1);
        spair[pos] = stageP[i];
    }
}

// ---------------- SpMM (CSR gather, one wave per row, lane = dim) ----------------
// MODE 0: layer 0 — gather from concat(embA,embB); y = a; acc = emb[r] + a
// MODE 1: mid layer — y = a; acc += a
// MODE 2: last layer — acc = 0.25*(acc + a); no y
// MODE 3: y = normalize(a)
// MODE 4: y = 0.5*normalize(a) + 0.5*base
template <int MODE>
__device__ __forceinline__ const float* gsrc(int c, const float* x, const float* embA,
                                             const float* embB, int split) {
    if (MODE == 0)
        return (c < split) ? embA + (((long long)c) << 6)
                           : embB + (((long long)(c - split)) << 6);
    return x + (((long long)c) << 6);
}

template <int MODE>
__global__ void k_spmm_csr(const int* __restrict__ rp, const int2* __restrict__ sp,
                           const float* __restrict__ x,
                           const float* __restrict__ embA, const float* __restrict__ embB,
                           float* __restrict__ y,
                           float* __restrict__ accU, float* __restrict__ accI,
                           const float* __restrict__ base, int split, int nrows) {
    int r = blockIdx.x * (blockDim.x >> 6) + (threadIdx.x >> 6);
    if (r >= nrows) return;
    int d = threadIdx.x & 63;
    int s = rp[r], e = rp[r + 1];
    float a = 0.f;
    int i = s;
    for (; i + 4 <= e; i += 4) {
        int2 p0 = sp[i], p1 = sp[i + 1], p2 = sp[i + 2], p3 = sp[i + 3];
        a += __int_as_float(p0.y) * gsrc<MODE>(p0.x, x, embA, embB, split)[d];
        a += __int_as_float(p1.y) * gsrc<MODE>(p1.x, x, embA, embB, split)[d];
        a += __int_as_float(p2.y) * gsrc<MODE>(p2.x, x, embA, embB, split)[d];
        a += __int_as_float(p3.y) * gsrc<MODE>(p3.x, x, embA, embB, split)[d];
    }
    for (; i < e; ++i) {
        int2 p = sp[i];
        a += __int_as_float(p.y) * gsrc<MODE>(p.x, x, embA, embB, split)[d];
    }
    long long off = (((long long)r) << 6) + d;
    if (MODE == 0) {
        y[off] = a;
        float e0 = (r < split) ? embA[off] : embB[off - (((long long)split) << 6)];
        if (r < split) accU[off] = e0 + a;
        else           accI[off - (((long long)split) << 6)] = e0 + a;
    } else if (MODE == 1) {
        y[off] = a;
        if (r < split) accU[off] += a;
        else           accI[off - (((long long)split) << 6)] += a;
    } else if (MODE == 2) {
        if (r < split) accU[off] = 0.25f * (accU[off] + a);
        else {
            long long o2 = off - (((long long)split) << 6);
            accI[o2] = 0.25f * (accI[o2] + a);
        }
    } else {
        float sq = a * a;
        for (int m = 32; m; m >>= 1) sq += __shfl_xor(sq, m);
        float inv = 1.0f / fmaxf(sqrtf(sq), 1e-12f);
        if (MODE == 3) y[off] = a * inv;
        else           y[off] = 0.5f * a * inv + 0.5f * base[off];
    }
}

// ---------------- host ----------------

static inline int nblk(long long n, int b) { return (int)((n + b - 1) / b); }
static inline size_t al256(size_t x) { return (x + 255) & ~(size_t)255; }

extern "C" void kernel_launch(void* const* d_in, const int* in_sizes, int n_in,
                              void* d_out, int out_size, void* d_ws, size_t ws_size,
                              hipStream_t stream) {
    const float* emb_user   = (const float*)d_in[0];
    const float* emb_item   = (const float*)d_in[1];
    const float* emb_author = (const float*)d_in[2];
    const int*   g0r = (const int*)d_in[3];
    const int*   g0c = (const int*)d_in[4];
    const float* g0v = (const float*)d_in[5];
    const int*   g1r = (const int*)d_in[6];
    const int*   g1c = (const int*)d_in[7];
    const float* g1v = (const float*)d_in[8];
    const int*   g3r = (const int*)d_in[9];
    const int*   g3c = (const int*)d_in[10];
    const float* g3v = (const float*)d_in[11];
    const int*   g4r = (const int*)d_in[12];
    const int*   g4c = (const int*)d_in[13];
    const float* g4v = (const float*)d_in[14];
    const int*   g5r = (const int*)d_in[15];
    const int*   g5c = (const int*)d_in[16];
    const float* g5v = (const float*)d_in[17];

    const int E0 = in_sizes[3];
    const int E1 = in_sizes[6];
    const int E3 = in_sizes[9];
    const int E4 = in_sizes[12];
    const int E5 = in_sizes[15];

    float* out = (float*)d_out;

    // ---- workspace carve-up ----
    char* w = (char*)d_ws;
    int*  rp     = (int*)w;  w += al256((size_t)(NN0 + 1) * 4);
    int*  cnt    = (int*)w;  w += al256((size_t)NN0 * 4);
    int*  excl   = (int*)w;  w += al256((size_t)NN0 * 4);
    int*  bsum   = (int*)w;  w += al256((size_t)1024 * 4);
    int*  bktCur = (int*)w;  w += al256((size_t)((NN0 >> BKS) + 2) * 4);
    int2* spair  = (int2*)w; w += al256((size_t)6400000 * 8);
    float* curb  = (float*)w; w += al256((size_t)NN0 * DD * 4);
    float* nxtb  = (float*)w; w += al256((size_t)NN0 * DD * 4);
    float* items0 = (float*)w; w += al256((size_t)NIi * DD * 4);
    // staging (dead whenever curb/nxtb hold live layer data — builds precede use)
    int*  stageR = (int*)curb;                                   // E*4  (<= 25.6MB)
    int2* stageP = (int2*)((char*)curb + al256((size_t)6400000 * 4)); // E*8 (<= 51.2MB)

    const int B = 256;

    auto build_csr = [&](const int* row, const int* col, const float* val, int E, int N) {
        int nbkt = (N + (1 << BKS) - 1) >> BKS;
        hipMemsetAsync(cnt, 0, (size_t)N * sizeof(int), stream);
        k_hist<<<nblk(E, B), B, 0, stream>>>(row, cnt, E);
        int nb = (N + 255) / 256;
        k_scan1<<<nb, 256, 0, stream>>>(cnt, N, excl, bsum);
        k_scan2<<<1, 1024, 0, stream>>>(bsum, nb);
        k_scan3<<<nblk(N + 1, 256), 256, 0, stream>>>(excl, bsum, N, E, rp);
        k_bktinit<<<nblk(nbkt, 256), 256, 0, stream>>>(rp, bktCur, nbkt);
        k_scatter1<<<nblk(E, B), B, 0, stream>>>(row, col, val, bktCur, stageR, stageP, E);
        k_scatter2<<<nbkt, 256, 0, stream>>>(rp, stageR, stageP, spair, N);
    };

    float* oUserA = out;                            // atom_users
    float* oUserN = out + (long long)NUu * DD;      // non_atom_users
    float* oItemA = out + (long long)200000 * DD;   // atom_items
    float* oItemN = out + (long long)300000 * DD;   // non_atom_items
    float* oAuthA = out + (long long)400000 * DD;   // atom_authors
    float* oAuthN = out + (long long)410000 * DD;   // non_atom_authors

    // ========== atom branch: 3-layer propagate on g0 ==========
    build_csr(g0r, g0c, g0v, E0, NN0);
    k_spmm_csr<0><<<nblk(NN0, 4), B, 0, stream>>>(rp, spair, nullptr, emb_user, emb_item,
                                                  curb, oUserA, items0, nullptr, NUu, NN0);
    k_spmm_csr<1><<<nblk(NN0, 4), B, 0, stream>>>(rp, spair, curb, nullptr, nullptr,
                                                  nxtb, oUserA, items0, nullptr, NUu, NN0);
    k_spmm_csr<2><<<nblk(NN0, 4), B, 0, stream>>>(rp, spair, nxtb, nullptr, nullptr,
                                                  nullptr, oUserA, items0, nullptr, NUu, NN0);

    // ========== non-atom branch: 3-layer propagate on g1 ==========
    build_csr(g1r, g1c, g1v, E1, NN1);
    k_spmm_csr<0><<<nblk(NN1, 4), B, 0, stream>>>(rp, spair, nullptr, emb_user, emb_author,
                                                  curb, oUserN, oAuthN, nullptr, NUu, NN1);
    k_spmm_csr<1><<<nblk(NN1, 4), B, 0, stream>>>(rp, spair, curb, nullptr, nullptr,
                                                  nxtb, oUserN, oAuthN, nullptr, NUu, NN1);
    k_spmm_csr<2><<<nblk(NN1, 4), B, 0, stream>>>(rp, spair, nxtb, nullptr, nullptr,
                                                  nullptr, oUserN, oAuthN, nullptr, NUu, NN1);

    // ========== atom_authors = normalize(g3 @ items0) ==========
    build_csr(g3r, g3c, g3v, E3, NAa);
    k_spmm_csr<3><<<nblk(NAa, 4), B, 0, stream>>>(rp, spair, items0, nullptr, nullptr,
                                                  oAuthA, nullptr, nullptr, nullptr, 0, NAa);

    // ========== atom_items = 0.5*normalize(g5 @ items0) + 0.5*items0 ==========
    build_csr(g5r, g5c, g5v, E5, NIi);
    k_spmm_csr<4><<<nblk(NIi, 4), B, 0, stream>>>(rp, spair, items0, nullptr, nullptr,
                                                  oItemA, nullptr, nullptr, items0, 0, NIi);

    // ========== non_atom_items = normalize(g4 @ non_atom_authors) ==========
    build_csr(g4r, g4c, g4v, E4, NIi);
    k_spmm_csr<3><<<nblk(NIi, 4), B, 0, stream>>>(rp, spair, oAuthN, nullptr, nullptr,
                                                  oItemN, nullptr, nullptr, nullptr, 0, NIi);
}

// Round 4
// 2517.362 us; speedup vs baseline: 1.6813x; 1.6813x over previous
//
#include <hip/hip_runtime.h>

#define NUu 100000
#define NIi 100000
#define NAa 10000
#define DD  64
#define NN0 (NUu + NIi)   // 200000
#define NN1 (NUu + NAa)   // 110000

// ---------------- CSR build kernels ----------------

__global__ void k_hist(const int* __restrict__ row, int* __restrict__ cnt, int E) {
    int e = blockIdx.x * blockDim.x + threadIdx.x;
    if (e >= E) return;
    atomicAdd(cnt + row[e], 1);   // fire-and-forget: pipelined, fast
}

// per-block exclusive scan (256 elems/block), block sums out
__global__ void k_scan1(const int* __restrict__ cnt, int n,
                        int* __restrict__ excl, int* __restrict__ bsum) {
    __shared__ int s[256];
    int gid = blockIdx.x * 256 + threadIdx.x;
    int v = (gid < n) ? cnt[gid] : 0;
    s[threadIdx.x] = v;
    __syncthreads();
    for (int off = 1; off < 256; off <<= 1) {
        int t = (threadIdx.x >= off) ? s[threadIdx.x - off] : 0;
        __syncthreads();
        s[threadIdx.x] += t;
        __syncthreads();
    }
    if (gid < n) excl[gid] = s[threadIdx.x] - v;
    if (threadIdx.x == 255) bsum[blockIdx.x] = s[255];
}

// single-block exclusive scan of block sums (nb <= 1024)
__global__ void k_scan2(int* __restrict__ bsum, int nb) {
    __shared__ int s[1024];
    int v = (threadIdx.x < nb) ? bsum[threadIdx.x] : 0;
    s[threadIdx.x] = v;
    __syncthreads();
    for (int off = 1; off < 1024; off <<= 1) {
        int t = (threadIdx.x >= off) ? s[threadIdx.x - off] : 0;
        __syncthreads();
        s[threadIdx.x] += t;
        __syncthreads();
    }
    if (threadIdx.x < nb) bsum[threadIdx.x] = s[threadIdx.x] - v;
}

// combine -> row_ptr; rp[n] = E; also bin cursors binCur[b] = rp[b<<shift]
__global__ void k_scan3(const int* __restrict__ excl, const int* __restrict__ bsum,
                        int n, int E, int* __restrict__ rp,
                        int* __restrict__ binCur, int shift) {
    int gid = blockIdx.x * 256 + threadIdx.x;
    if (gid < n) {
        int v = excl[gid] + bsum[gid >> 8];
        rp[gid] = v;
        if ((gid & ((1 << shift) - 1)) == 0) binCur[gid >> shift] = v;
    }
    if (gid == n) rp[n] = E;
}

// P1: partition edges into per-bin staged segments.
// Per block: LDS histogram over bins -> one returning global atomic per (block,bin)
// -> LDS-ticketed staging writes (per-bin contiguous runs).
#define P1_ITER 8
__global__ void __launch_bounds__(1024)
k_part1(const int* __restrict__ row, const int* __restrict__ col,
        const float* __restrict__ val, int* __restrict__ binCur,
        int* __restrict__ stageR, int2* __restrict__ stageP,
        int E, int shift, int nbins) {
    __shared__ int h[512];
    int base = blockIdx.x * (blockDim.x * P1_ITER);
    for (int t = threadIdx.x; t < nbins; t += blockDim.x) h[t] = 0;
    __syncthreads();
    int e0 = base + threadIdx.x;
    int r[P1_ITER];
#pragma unroll
    for (int i = 0; i < P1_ITER; ++i) {
        int e = e0 + i * blockDim.x;
        r[i] = (e < E) ? row[e] : -1;
        if (r[i] >= 0) atomicAdd(&h[r[i] >> shift], 1);
    }
    __syncthreads();
    for (int t = threadIdx.x; t < nbins; t += blockDim.x) {
        int c = h[t];
        h[t] = c ? atomicAdd(binCur + t, c) : 0;
    }
    __syncthreads();
#pragma unroll
    for (int i = 0; i < P1_ITER; ++i) {
        int e = e0 + i * blockDim.x;
        if (e < E) {
            int rr = r[i];
            int pos = atomicAdd(&h[rr >> shift], 1);
            stageR[pos] = rr;
            int2 p;
            p.x = col[e];
            p.y = __float_as_int(val[e]);
            stageP[pos] = p;
        }
    }
}

// P2: one block per bin; exact CSR placement via LDS row cursors.
__global__ void __launch_bounds__(1024)
k_part2(const int* __restrict__ rp, const int* __restrict__ stageR,
        const int2* __restrict__ stageP, int2* __restrict__ spair,
        int N, int shift) {
    __shared__ int cur[512];
    int rbase = blockIdx.x << shift;
    int rpb = 1 << shift;
    int nr = min(rpb, N - rbase);
    for (int t = threadIdx.x; t < nr; t += blockDim.x) cur[t] = rp[rbase + t];
    __syncthreads();
    int es = rp[rbase];
    int ee = rp[rbase + nr];
    for (int i = es + (int)threadIdx.x; i < ee; i += blockDim.x) {
        int r = stageR[i];
        int pos = atomicAdd(&cur[r - rbase], 1);
        spair[pos] = stageP[i];
    }
}

// ---------------- SpMM (CSR gather, one wave per row, lane = dim) ----------------
// MODE 0: layer 0 — gather from concat(embA,embB); y = a; acc = emb[r] + a
// MODE 1: mid layer — y = a; acc += a
// MODE 2: last layer — acc = 0.25*(acc + a); no y
// MODE 3: y = normalize(a)
// MODE 4: y = 0.5*normalize(a) + 0.5*base
template <int MODE>
__device__ __forceinline__ const float* gsrc(int c, const float* x, const float* embA,
                                             const float* embB, int split) {
    if (MODE == 0)
        return (c < split) ? embA + (((long long)c) << 6)
                           : embB + (((long long)(c - split)) << 6);
    return x + (((long long)c) << 6);
}

template <int MODE>
__global__ void k_spmm_csr(const int* __restrict__ rp, const int2* __restrict__ sp,
                           const float* __restrict__ x,
                           const float* __restrict__ embA, const float* __restrict__ embB,
                           float* __restrict__ y,
                           float* __restrict__ accU, float* __restrict__ accI,
                           const float* __restrict__ base, int split, int nrows) {
    int r = blockIdx.x * (blockDim.x >> 6) + (threadIdx.x >> 6);
    if (r >= nrows) return;
    int d = threadIdx.x & 63;
    int s = rp[r], e = rp[r + 1];
    float a = 0.f;
    int i = s;
    for (; i + 4 <= e; i += 4) {
        int2 p0 = sp[i], p1 = sp[i + 1], p2 = sp[i + 2], p3 = sp[i + 3];
        a += __int_as_float(p0.y) * gsrc<MODE>(p0.x, x, embA, embB, split)[d];
        a += __int_as_float(p1.y) * gsrc<MODE>(p1.x, x, embA, embB, split)[d];
        a += __int_as_float(p2.y) * gsrc<MODE>(p2.x, x, embA, embB, split)[d];
        a += __int_as_float(p3.y) * gsrc<MODE>(p3.x, x, embA, embB, split)[d];
    }
    for (; i < e; ++i) {
        int2 p = sp[i];
        a += __int_as_float(p.y) * gsrc<MODE>(p.x, x, embA, embB, split)[d];
    }
    long long off = (((long long)r) << 6) + d;
    if (MODE == 0) {
        y[off] = a;
        float e0 = (r < split) ? embA[off] : embB[off - (((long long)split) << 6)];
        if (r < split) accU[off] = e0 + a;
        else           accI[off - (((long long)split) << 6)] = e0 + a;
    } else if (MODE == 1) {
        y[off] = a;
        if (r < split) accU[off] += a;
        else           accI[off - (((long long)split) << 6)] += a;
    } else if (MODE == 2) {
        if (r < split) accU[off] = 0.25f * (accU[off] + a);
        else {
            long long o2 = off - (((long long)split) << 6);
            accI[o2] = 0.25f * (accI[o2] + a);
        }
    } else {
        float sq = a * a;
        for (int m = 32; m; m >>= 1) sq += __shfl_xor(sq, m);
        float inv = 1.0f / fmaxf(sqrtf(sq), 1e-12f);
        if (MODE == 3) y[off] = a * inv;
        else           y[off] = 0.5f * a * inv + 0.5f * base[off];
    }
}

// ---------------- host ----------------

static inline int nblk(long long n, int b) { return (int)((n + b - 1) / b); }
static inline size_t al256(size_t x) { return (x + 255) & ~(size_t)255; }

extern "C" void kernel_launch(void* const* d_in, const int* in_sizes, int n_in,
                              void* d_out, int out_size, void* d_ws, size_t ws_size,
                              hipStream_t stream) {
    const float* emb_user   = (const float*)d_in[0];
    const float* emb_item   = (const float*)d_in[1];
    const float* emb_author = (const float*)d_in[2];
    const int*   g0r = (const int*)d_in[3];
    const int*   g0c = (const int*)d_in[4];
    const float* g0v = (const float*)d_in[5];
    const int*   g1r = (const int*)d_in[6];
    const int*   g1c = (const int*)d_in[7];
    const float* g1v = (const float*)d_in[8];
    const int*   g3r = (const int*)d_in[9];
    const int*   g3c = (const int*)d_in[10];
    const float* g3v = (const float*)d_in[11];
    const int*   g4r = (const int*)d_in[12];
    const int*   g4c = (const int*)d_in[13];
    const float* g4v = (const float*)d_in[14];
    const int*   g5r = (const int*)d_in[15];
    const int*   g5c = (const int*)d_in[16];
    const float* g5v = (const float*)d_in[17];

    const int E0 = in_sizes[3];
    const int E1 = in_sizes[6];
    const int E3 = in_sizes[9];
    const int E4 = in_sizes[12];
    const int E5 = in_sizes[15];

    float* out = (float*)d_out;

    // ---- workspace carve-up ----
    char* w = (char*)d_ws;
    int*  rp     = (int*)w;  w += al256((size_t)(NN0 + 1) * 4);
    int*  cnt    = (int*)w;  w += al256((size_t)NN0 * 4);
    int*  excl   = (int*)w;  w += al256((size_t)NN0 * 4);
    int*  bsum   = (int*)w;  w += al256((size_t)1024 * 4);
    int*  binCur = (int*)w;  w += al256((size_t)1024 * 4);
    int2* spair  = (int2*)w; w += al256((size_t)6400000 * 8);
    float* curb  = (float*)w; w += al256((size_t)NN0 * DD * 4);
    float* nxtb  = (float*)w; w += al256((size_t)NN0 * DD * 4);
    float* items0 = (float*)w; w += al256((size_t)NIi * DD * 4);
    // staging aliases curb/nxtb (dead during builds)
    int*  stageR = (int*)curb;                                        // E*4  (<= 25.6MB)
    int2* stageP = (int2*)((char*)curb + al256((size_t)6400000 * 4)); // E*8  (<= 51.2MB)

    const int B = 256;

    // shift: rows-per-bin = 1<<shift; nbins = ceil(N / 2^shift) (<= 512)
    auto build_csr = [&](const int* row, const int* col, const float* val,
                         int E, int N, int shift) {
        int nbins = (N + (1 << shift) - 1) >> shift;
        hipMemsetAsync(cnt, 0, (size_t)N * sizeof(int), stream);
        k_hist<<<nblk(E, B), B, 0, stream>>>(row, cnt, E);
        int nb = (N + 255) / 256;
        k_scan1<<<nb, 256, 0, stream>>>(cnt, N, excl, bsum);
        k_scan2<<<1, 1024, 0, stream>>>(bsum, nb);
        k_scan3<<<nblk(N + 1, 256), 256, 0, stream>>>(excl, bsum, N, E, rp, binCur, shift);
        k_part1<<<nblk(E, 1024 * P1_ITER), 1024, 0, stream>>>(row, col, val, binCur,
                                                              stageR, stageP, E, shift, nbins);
        k_part2<<<nbins, 1024, 0, stream>>>(rp, stageR, stageP, spair, N, shift);
    };

    float* oUserA = out;                            // atom_users
    float* oUserN = out + (long long)NUu * DD;      // non_atom_users
    float* oItemA = out + (long long)200000 * DD;   // atom_items
    float* oItemN = out + (long long)300000 * DD;   // non_atom_items
    float* oAuthA = out + (long long)400000 * DD;   // atom_authors
    float* oAuthN = out + (long long)410000 * DD;   // non_atom_authors

    // ========== atom branch: 3-layer propagate on g0 ==========
    build_csr(g0r, g0c, g0v, E0, NN0, 9);   // 391 bins
    k_spmm_csr<0><<<nblk(NN0, 4), B, 0, stream>>>(rp, spair, nullptr, emb_user, emb_item,
                                                  curb, oUserA, items0, nullptr, NUu, NN0);
    k_spmm_csr<1><<<nblk(NN0, 4), B, 0, stream>>>(rp, spair, curb, nullptr, nullptr,
                                                  nxtb, oUserA, items0, nullptr, NUu, NN0);
    k_spmm_csr<2><<<nblk(NN0, 4), B, 0, stream>>>(rp, spair, nxtb, nullptr, nullptr,
                                                  nullptr, oUserA, items0, nullptr, NUu, NN0);

    // ========== non-atom branch: 3-layer propagate on g1 ==========
    build_csr(g1r, g1c, g1v, E1, NN1, 9);   // 215 bins
    k_spmm_csr<0><<<nblk(NN1, 4), B, 0, stream>>>(rp, spair, nullptr, emb_user, emb_author,
                                                  curb, oUserN, oAuthN, nullptr, NUu, NN1);
    k_spmm_csr<1><<<nblk(NN1, 4), B, 0, stream>>>(rp, spair, curb, nullptr, nullptr,
                                                  nxtb, oUserN, oAuthN, nullptr, NUu, NN1);
    k_spmm_csr<2><<<nblk(NN1, 4), B, 0, stream>>>(rp, spair, nxtb, nullptr, nullptr,
                                                  nullptr, oUserN, oAuthN, nullptr, NUu, NN1);

    // ========== atom_authors = normalize(g3 @ items0) ==========
    build_csr(g3r, g3c, g3v, E3, NAa, 5);   // 313 bins
    k_spmm_csr<3><<<nblk(NAa, 4), B, 0, stream>>>(rp, spair, items0, nullptr, nullptr,
                                                  oAuthA, nullptr, nullptr, nullptr, 0, NAa);

    // ========== atom_items = 0.5*normalize(g5 @ items0) + 0.5*items0 ==========
    build_csr(g5r, g5c, g5v, E5, NIi, 8);   // 391 bins
    k_spmm_csr<4><<<nblk(NIi, 4), B, 0, stream>>>(rp, spair, items0, nullptr, nullptr,
                                                  oItemA, nullptr, nullptr, items0, 0, NIi);

    // ========== non_atom_items = normalize(g4 @ non_atom_authors) ==========
    build_csr(g4r, g4c, g4v, E4, NIi, 8);   // 391 bins
    k_spmm_csr<3><<<nblk(NIi, 4), B, 0, stream>>>(rp, spair, oAuthN, nullptr, nullptr,
                                                  oItemN, nullptr, nullptr, nullptr, 0, NIi);
}

// Round 5
// 2071.466 us; speedup vs baseline: 2.0433x; 1.2153x over previous
//
#include <hip/hip_runtime.h>

#define NUu 100000
#define NIi 100000
#define NAa 10000
#define DD  64
#define NN0 (NUu + NIi)   // 200000
#define NN1 (NUu + NAa)   // 110000

typedef unsigned int uint;

// ---------------- bf16 helpers ----------------

__device__ __forceinline__ uint pack_bf2(float x, float y) {
    uint a = __float_as_uint(x);
    uint b = __float_as_uint(y);
    a = (a + 0x7fffu + ((a >> 16) & 1u)) >> 16;          // RNE low half
    b = (b + 0x7fffu + ((b >> 16) & 1u)) & 0xffff0000u;  // RNE high half
    return (a & 0xffffu) | b;
}
__device__ __forceinline__ float bflo(uint w) { return __uint_as_float(w << 16); }
__device__ __forceinline__ float bfhi(uint w) { return __uint_as_float(w & 0xffff0000u); }

// convert fp32 -> packed bf16x2 (float4 -> uint2), n4 = nfloats/4
__global__ void k_f2bf(const float4* __restrict__ src, uint2* __restrict__ dst, int n4) {
    int i = blockIdx.x * blockDim.x + threadIdx.x;
    if (i >= n4) return;
    float4 v = src[i];
    uint2 o;
    o.x = pack_bf2(v.x, v.y);
    o.y = pack_bf2(v.z, v.w);
    dst[i] = o;
}

// ---------------- CSR build kernels ----------------

__global__ void k_hist(const int* __restrict__ row, int* __restrict__ cnt, int E) {
    int e = blockIdx.x * blockDim.x + threadIdx.x;
    if (e >= E) return;
    atomicAdd(cnt + row[e], 1);   // fire-and-forget
}

__global__ void k_scan1(const int* __restrict__ cnt, int n,
                        int* __restrict__ excl, int* __restrict__ bsum) {
    __shared__ int s[256];
    int gid = blockIdx.x * 256 + threadIdx.x;
    int v = (gid < n) ? cnt[gid] : 0;
    s[threadIdx.x] = v;
    __syncthreads();
    for (int off = 1; off < 256; off <<= 1) {
        int t = (threadIdx.x >= off) ? s[threadIdx.x - off] : 0;
        __syncthreads();
        s[threadIdx.x] += t;
        __syncthreads();
    }
    if (gid < n) excl[gid] = s[threadIdx.x] - v;
    if (threadIdx.x == 255) bsum[blockIdx.x] = s[255];
}

__global__ void k_scan2(int* __restrict__ bsum, int nb) {
    __shared__ int s[1024];
    int v = (threadIdx.x < nb) ? bsum[threadIdx.x] : 0;
    s[threadIdx.x] = v;
    __syncthreads();
    for (int off = 1; off < 1024; off <<= 1) {
        int t = (threadIdx.x >= off) ? s[threadIdx.x - off] : 0;
        __syncthreads();
        s[threadIdx.x] += t;
        __syncthreads();
    }
    if (threadIdx.x < nb) bsum[threadIdx.x] = s[threadIdx.x] - v;
}

__global__ void k_scan3(const int* __restrict__ excl, const int* __restrict__ bsum,
                        int n, int E, int* __restrict__ rp,
                        int* __restrict__ binCur, int shift) {
    int gid = blockIdx.x * 256 + threadIdx.x;
    if (gid < n) {
        int v = excl[gid] + bsum[gid >> 8];
        rp[gid] = v;
        if ((gid & ((1 << shift) - 1)) == 0) binCur[gid >> shift] = v;
    }
    if (gid == n) rp[n] = E;
}

// P1: partition edges into per-bin staged segments; stage = {rowlow<<18 | col, val}
#define P1_ITER 8
__global__ void __launch_bounds__(1024)
k_part1(const int* __restrict__ row, const int* __restrict__ col,
        const float* __restrict__ val, int* __restrict__ binCur,
        int2* __restrict__ stageP, int E, int shift, int nbins) {
    __shared__ int h[512];
    int base = blockIdx.x * (blockDim.x * P1_ITER);
    for (int t = threadIdx.x; t < nbins; t += blockDim.x) h[t] = 0;
    __syncthreads();
    int e0 = base + threadIdx.x;
    int r[P1_ITER];
#pragma unroll
    for (int i = 0; i < P1_ITER; ++i) {
        int e = e0 + i * blockDim.x;
        r[i] = (e < E) ? row[e] : -1;
        if (r[i] >= 0) atomicAdd(&h[r[i] >> shift], 1);
    }
    __syncthreads();
    for (int t = threadIdx.x; t < nbins; t += blockDim.x) {
        int c = h[t];
        h[t] = c ? atomicAdd(binCur + t, c) : 0;
    }
    __syncthreads();
#pragma unroll
    for (int i = 0; i < P1_ITER; ++i) {
        int e = e0 + i * blockDim.x;
        if (e < E) {
            int rr = r[i];
            int pos = atomicAdd(&h[rr >> shift], 1);
            int2 p;
            p.x = ((rr & ((1 << shift) - 1)) << 18) | col[e];
            p.y = __float_as_int(val[e]);
            stageP[pos] = p;
        }
    }
}

// P2: one block per bin; exact CSR placement via LDS row cursors
__global__ void __launch_bounds__(1024)
k_part2(const int* __restrict__ rp, const int2* __restrict__ stageP,
        int2* __restrict__ spair, int N, int shift) {
    __shared__ int cur[512];
    int rbase = blockIdx.x << shift;
    int nr = min(1 << shift, N - rbase);
    for (int t = threadIdx.x; t < nr; t += blockDim.x) cur[t] = rp[rbase + t];
    __syncthreads();
    int es = rp[rbase];
    int ee = rp[rbase + nr];
    for (int i = es + (int)threadIdx.x; i < ee; i += blockDim.x) {
        int2 p = stageP[i];
        int pos = atomicAdd(&cur[p.x >> 18], 1);
        int2 o;
        o.x = p.x & 0x3ffff;
        o.y = p.y;
        spair[pos] = o;
    }
}

// ---------------- SpMM (bf16 gather, one wave = one row, 2 edges/step) ----------------
// lane = half*32 + dp : half selects edge parity, dp selects dim pair (dims 2dp, 2dp+1)
// MODE 0: plain  — ob = pack(a)
// MODE 1: final  — out = 0.25*(emb + y1 + y2 + a); fp32 out split U/I, optional bf16 outIb
// MODE 2: norm   — yf = normalize(a)
// MODE 3: blend  — yf = 0.5*normalize(a) + 0.5*base
template <int MODE>
__global__ void k_spmm(const int* __restrict__ rp, const int2* __restrict__ sp,
                       const uint* __restrict__ xb,
                       const float* __restrict__ embA, const float* __restrict__ embB,
                       const uint* __restrict__ y1b, const uint* __restrict__ y2b,
                       float* __restrict__ outU, float* __restrict__ outI,
                       uint* __restrict__ outIb,
                       uint* __restrict__ ob, float* __restrict__ yf,
                       const float* __restrict__ base, int split, int nrows) {
    int r = blockIdx.x * (blockDim.x >> 6) + (threadIdx.x >> 6);
    if (r >= nrows) return;
    int lane = threadIdx.x & 63;
    int half = lane >> 5;
    int dp = lane & 31;

    int s0 = rp[r], e0 = rp[r + 1];
    float ax = 0.f, ay = 0.f;
    int i = s0;
    for (; i + 4 <= e0; i += 4) {
        int2 pa = sp[i + half];
        int2 pb = sp[i + 2 + half];
        uint wa = xb[(((long long)pa.x) << 5) + dp];
        uint wb = xb[(((long long)pb.x) << 5) + dp];
        float va = __int_as_float(pa.y);
        float vb = __int_as_float(pb.y);
        ax += va * bflo(wa); ay += va * bfhi(wa);
        ax += vb * bflo(wb); ay += vb * bfhi(wb);
    }
    for (; i < e0; i += 2) {
        int2 p;
        if (i + 1 < e0) p = sp[i + half];
        else if (half == 0) p = sp[i];
        else { p.x = 0; p.y = 0; }           // val=0 pad
        uint w = xb[(((long long)p.x) << 5) + dp];
        float v = __int_as_float(p.y);
        ax += v * bflo(w); ay += v * bfhi(w);
    }
    ax += __shfl_xor(ax, 32);
    ay += __shfl_xor(ay, 32);

    long long off2 = (((long long)r) << 6) + 2 * dp;

    if (MODE == 0) {
        if (half == 0) ob[(((long long)r) << 5) + dp] = pack_bf2(ax, ay);
    } else if (MODE == 1) {
        if (half == 0) {
            long long oE = off2;
            float2 e2;
            if (r < split) e2 = *(const float2*)(embA + oE);
            else           e2 = *(const float2*)(embB + (oE - (((long long)split) << 6)));
            uint w1 = y1b[(((long long)r) << 5) + dp];
            uint w2 = y2b[(((long long)r) << 5) + dp];
            float sx = 0.25f * (e2.x + bflo(w1) + bflo(w2) + ax);
            float sy = 0.25f * (e2.y + bfhi(w1) + bfhi(w2) + ay);
            if (r < split) {
                float2 o; o.x = sx; o.y = sy;
                *(float2*)(outU + off2) = o;
            } else {
                long long o2 = off2 - (((long long)split) << 6);
                float2 o; o.x = sx; o.y = sy;
                *(float2*)(outI + o2) = o;
                if (outIb) outIb[(((long long)(r - split)) << 5) + dp] = pack_bf2(sx, sy);
            }
        }
    } else {
        float sq = ax * ax + ay * ay;
        for (int m = 16; m; m >>= 1) sq += __shfl_xor(sq, m);
        float inv = 1.0f / fmaxf(sqrtf(sq), 1e-12f);
        if (half == 0) {
            float2 o;
            if (MODE == 2) { o.x = ax * inv; o.y = ay * inv; }
            else {
                float2 b2 = *(const float2*)(base + off2);
                o.x = 0.5f * ax * inv + 0.5f * b2.x;
                o.y = 0.5f * ay * inv + 0.5f * b2.y;
            }
            *(float2*)(yf + off2) = o;
        }
    }
}

// ---------------- host ----------------

static inline int nblk(long long n, int b) { return (int)((n + b - 1) / b); }
static inline size_t al256(size_t x) { return (x + 255) & ~(size_t)255; }

extern "C" void kernel_launch(void* const* d_in, const int* in_sizes, int n_in,
                              void* d_out, int out_size, void* d_ws, size_t ws_size,
                              hipStream_t stream) {
    const float* emb_user   = (const float*)d_in[0];
    const float* emb_item   = (const float*)d_in[1];
    const float* emb_author = (const float*)d_in[2];
    const int*   g0r = (const int*)d_in[3];
    const int*   g0c = (const int*)d_in[4];
    const float* g0v = (const float*)d_in[5];
    const int*   g1r = (const int*)d_in[6];
    const int*   g1c = (const int*)d_in[7];
    const float* g1v = (const float*)d_in[8];
    const int*   g3r = (const int*)d_in[9];
    const int*   g3c = (const int*)d_in[10];
    const float* g3v = (const float*)d_in[11];
    const int*   g4r = (const int*)d_in[12];
    const int*   g4c = (const int*)d_in[13];
    const float* g4v = (const float*)d_in[14];
    const int*   g5r = (const int*)d_in[15];
    const int*   g5c = (const int*)d_in[16];
    const float* g5v = (const float*)d_in[17];

    const int E0 = in_sizes[3];
    const int E1 = in_sizes[6];
    const int E3 = in_sizes[9];
    const int E4 = in_sizes[12];
    const int E5 = in_sizes[15];

    float* out = (float*)d_out;

    // ---- workspace carve-up ----
    char* w = (char*)d_ws;
    int*  rp     = (int*)w;  w += al256((size_t)(NN0 + 1) * 4);
    int*  cnt    = (int*)w;  w += al256((size_t)NN0 * 4);
    int*  excl   = (int*)w;  w += al256((size_t)NN0 * 4);
    int*  bsum   = (int*)w;  w += al256((size_t)1024 * 4);
    int*  binCur = (int*)w;  w += al256((size_t)1024 * 4);
    int2* spair  = (int2*)w; w += al256((size_t)6400000 * 8);
    uint* xb0    = (uint*)w; w += al256((size_t)NN0 * 32 * 4);   // bf16 layer-0 input
    uint* y1b    = (uint*)w; w += al256((size_t)NN0 * 32 * 4);   // bf16 layer outs
    uint* y2b    = (uint*)w; w += al256((size_t)NN0 * 32 * 4);
    float* items0  = (float*)w; w += al256((size_t)NIi * DD * 4); // fp32 atom_items0
    uint*  items0b = (uint*)w;  w += al256((size_t)NIi * 32 * 4); // bf16 atom_items0
    uint*  oAuthNb = (uint*)w;  w += al256((size_t)NAa * 32 * 4); // bf16 non_atom_authors
    // staging aliases y1b+y2b (dead during builds): E*8 <= 51.2MB
    int2* stageP = (int2*)y1b;

    const int B = 256;

    auto build_csr = [&](const int* row, const int* col, const float* val,
                         int E, int N, int shift) {
        int nbins = (N + (1 << shift) - 1) >> shift;
        hipMemsetAsync(cnt, 0, (size_t)N * sizeof(int), stream);
        k_hist<<<nblk(E, B), B, 0, stream>>>(row, cnt, E);
        int nb = (N + 255) / 256;
        k_scan1<<<nb, 256, 0, stream>>>(cnt, N, excl, bsum);
        k_scan2<<<1, 1024, 0, stream>>>(bsum, nb);
        k_scan3<<<nblk(N + 1, 256), 256, 0, stream>>>(excl, bsum, N, E, rp, binCur, shift);
        k_part1<<<nblk(E, 1024 * P1_ITER), 1024, 0, stream>>>(row, col, val, binCur,
                                                              stageP, E, shift, nbins);
        k_part2<<<nbins, 1024, 0, stream>>>(rp, stageP, spair, N, shift);
    };

    float* oUserA = out;                            // atom_users
    float* oUserN = out + (long long)NUu * DD;      // non_atom_users
    float* oItemA = out + (long long)200000 * DD;   // atom_items
    float* oItemN = out + (long long)300000 * DD;   // non_atom_items
    float* oAuthA = out + (long long)400000 * DD;   // atom_authors
    float* oAuthN = out + (long long)410000 * DD;   // non_atom_authors

    // ========== atom branch: 3-layer propagate on g0 ==========
    build_csr(g0r, g0c, g0v, E0, NN0, 9);
    k_f2bf<<<nblk((long long)NUu * 16, B), B, 0, stream>>>((const float4*)emb_user,
                                                           (uint2*)xb0, NUu * 16);
    k_f2bf<<<nblk((long long)NIi * 16, B), B, 0, stream>>>((const float4*)emb_item,
                                                           (uint2*)(xb0 + (long long)NUu * 32),
                                                           NIi * 16);
    k_spmm<0><<<nblk(NN0, 4), B, 0, stream>>>(rp, spair, xb0, nullptr, nullptr, nullptr,
                                              nullptr, nullptr, nullptr, nullptr,
                                              y1b, nullptr, nullptr, NUu, NN0);
    k_spmm<0><<<nblk(NN0, 4), B, 0, stream>>>(rp, spair, y1b, nullptr, nullptr, nullptr,
                                              nullptr, nullptr, nullptr, nullptr,
                                              y2b, nullptr, nullptr, NUu, NN0);
    k_spmm<1><<<nblk(NN0, 4), B, 0, stream>>>(rp, spair, y2b, emb_user, emb_item,
                                              y1b, y2b, oUserA, items0, items0b,
                                              nullptr, nullptr, nullptr, NUu, NN0);

    // ========== non-atom branch: 3-layer propagate on g1 ==========
    build_csr(g1r, g1c, g1v, E1, NN1, 9);
    k_f2bf<<<nblk((long long)NUu * 16, B), B, 0, stream>>>((const float4*)emb_user,
                                                           (uint2*)xb0, NUu * 16);
    k_f2bf<<<nblk((long long)NAa * 16, B), B, 0, stream>>>((const float4*)emb_author,
                                                           (uint2*)(xb0 + (long long)NUu * 32),
                                                           NAa * 16);
    k_spmm<0><<<nblk(NN1, 4), B, 0, stream>>>(rp, spair, xb0, nullptr, nullptr, nullptr,
                                              nullptr, nullptr, nullptr, nullptr,
                                              y1b, nullptr, nullptr, NUu, NN1);
    k_spmm<0><<<nblk(NN1, 4), B, 0, stream>>>(rp, spair, y1b, nullptr, nullptr, nullptr,
                                              nullptr, nullptr, nullptr, nullptr,
                                              y2b, nullptr, nullptr, NUu, NN1);
    k_spmm<1><<<nblk(NN1, 4), B, 0, stream>>>(rp, spair, y2b, emb_user, emb_author,
                                              y1b, y2b, oUserN, oAuthN, oAuthNb,
                                              nullptr, nullptr, nullptr, NUu, NN1);

    // ========== atom_authors = normalize(g3 @ items0) ==========
    build_csr(g3r, g3c, g3v, E3, NAa, 5);
    k_spmm<2><<<nblk(NAa, 4), B, 0, stream>>>(rp, spair, items0b, nullptr, nullptr, nullptr,
                                              nullptr, nullptr, nullptr, nullptr,
                                              nullptr, oAuthA, nullptr, 0, NAa);

    // ========== atom_items = 0.5*normalize(g5 @ items0) + 0.5*items0 ==========
    build_csr(g5r, g5c, g5v, E5, NIi, 8);
    k_spmm<3><<<nblk(NIi, 4), B, 0, stream>>>(rp, spair, items0b, nullptr, nullptr, nullptr,
                                              nullptr, nullptr, nullptr, nullptr,
                                              nullptr, oItemA, items0, 0, NIi);

    // ========== non_atom_items = normalize(g4 @ non_atom_authors) ==========
    build_csr(g4r, g4c, g4v, E4, NIi, 8);
    k_spmm<2><<<nblk(NIi, 4), B, 0, stream>>>(rp, spair, oAuthNb, nullptr, nullptr, nullptr,
                                              nullptr, nullptr, nullptr, nullptr,
                                              nullptr, oItemN, nullptr, 0, NIi);
}

// Round 6
// 1560.163 us; speedup vs baseline: 2.7129x; 1.3277x over previous
//
#include <hip/hip_runtime.h>

#define NUu 100000
#define NIi 100000
#define NAa 10000
#define DD  64
#define NN0 (NUu + NIi)   // 200000
#define NN1 (NUu + NAa)   // 110000

typedef unsigned int uint;

// ---------------- bf16 helpers ----------------

__device__ __forceinline__ uint pack_bf2(float x, float y) {
    uint a = __float_as_uint(x);
    uint b = __float_as_uint(y);
    a = (a + 0x7fffu + ((a >> 16) & 1u)) >> 16;          // RNE low half
    b = (b + 0x7fffu + ((b >> 16) & 1u)) & 0xffff0000u;  // RNE high half
    return (a & 0xffffu) | b;
}
__device__ __forceinline__ float bflo(uint w) { return __uint_as_float(w << 16); }
__device__ __forceinline__ float bfhi(uint w) { return __uint_as_float(w & 0xffff0000u); }

// convert fp32 -> packed bf16x2 (float4 -> uint2), n4 = nfloats/4
__global__ void k_f2bf(const float4* __restrict__ src, uint2* __restrict__ dst, int n4) {
    int i = blockIdx.x * blockDim.x + threadIdx.x;
    if (i >= n4) return;
    float4 v = src[i];
    uint2 o;
    o.x = pack_bf2(v.x, v.y);
    o.y = pack_bf2(v.z, v.w);
    dst[i] = o;
}

// ---------------- CSR build (bin-partition, no global row histogram) ----------------

#define P1_ITER 8

// per-block LDS histogram over bins -> one global add per (block,bin)
__global__ void __launch_bounds__(1024)
k_binhist(const int* __restrict__ row, int* __restrict__ binCnt,
          int E, int shift, int nbins) {
    __shared__ int h[512];
    for (int t = threadIdx.x; t < nbins; t += blockDim.x) h[t] = 0;
    __syncthreads();
    int e0 = blockIdx.x * (blockDim.x * P1_ITER) + threadIdx.x;
#pragma unroll
    for (int i = 0; i < P1_ITER; ++i) {
        int e = e0 + i * blockDim.x;
        if (e < E) atomicAdd(&h[row[e] >> shift], 1);
    }
    __syncthreads();
    for (int t = threadIdx.x; t < nbins; t += blockDim.x)
        if (h[t]) atomicAdd(binCnt + t, h[t]);
}

// single-block exclusive scan of bin counts -> binBase (nbins+1), binCur
__global__ void k_binscan(const int* __restrict__ binCnt, int* __restrict__ binBase,
                          int* __restrict__ binCur, int nbins, int E) {
    __shared__ int s[512];
    int tid = threadIdx.x;
    int v = (tid < nbins) ? binCnt[tid] : 0;
    s[tid] = v;
    __syncthreads();
    for (int off = 1; off < 512; off <<= 1) {
        int t = (tid >= off) ? s[tid - off] : 0;
        __syncthreads();
        s[tid] += t;
        __syncthreads();
    }
    if (tid < nbins) {
        int b = s[tid] - v;
        binBase[tid] = b;
        binCur[tid] = b;
    }
    if (tid == 0) binBase[nbins] = E;
}

// P1: partition edges into per-bin staged segments; stage = {rowlow<<18 | col, val}
__global__ void __launch_bounds__(1024)
k_part1(const int* __restrict__ row, const int* __restrict__ col,
        const float* __restrict__ val, int* __restrict__ binCur,
        int2* __restrict__ stageP, int E, int shift, int nbins) {
    __shared__ int h[512];
    for (int t = threadIdx.x; t < nbins; t += blockDim.x) h[t] = 0;
    __syncthreads();
    int e0 = blockIdx.x * (blockDim.x * P1_ITER) + threadIdx.x;
    int r[P1_ITER];
#pragma unroll
    for (int i = 0; i < P1_ITER; ++i) {
        int e = e0 + i * blockDim.x;
        r[i] = (e < E) ? row[e] : -1;
        if (r[i] >= 0) atomicAdd(&h[r[i] >> shift], 1);
    }
    __syncthreads();
    for (int t = threadIdx.x; t < nbins; t += blockDim.x) {
        int c = h[t];
        h[t] = c ? atomicAdd(binCur + t, c) : 0;
    }
    __syncthreads();
#pragma unroll
    for (int i = 0; i < P1_ITER; ++i) {
        int e = e0 + i * blockDim.x;
        if (e < E) {
            int rr = r[i];
            int pos = atomicAdd(&h[rr >> shift], 1);
            int2 p;
            p.x = ((rr & ((1 << shift) - 1)) << 18) | col[e];
            p.y = __float_as_int(val[e]);
            stageP[pos] = p;
        }
    }
}

// P2: one block per bin. Count per-row in LDS, scan -> write rp, then exact placement.
__global__ void __launch_bounds__(1024)
k_part2(const int* __restrict__ binBase, const int2* __restrict__ stageP,
        int2* __restrict__ spair, int* __restrict__ rp, int N, int shift) {
    __shared__ int h[512];
    __shared__ int s[512];
    int tid = threadIdx.x;
    int rbase = blockIdx.x << shift;
    int nr = min(1 << shift, N - rbase);
    int es = binBase[blockIdx.x];
    int ee = binBase[blockIdx.x + 1];
    if (tid < 512) h[tid] = 0;
    __syncthreads();
    for (int i = es + tid; i < ee; i += blockDim.x)
        atomicAdd(&h[stageP[i].x >> 18], 1);
    __syncthreads();
    // exclusive scan of 512 counts (first 512 threads)
    int v = (tid < 512) ? h[tid] : 0;
    if (tid < 512) s[tid] = v;
    __syncthreads();
    for (int off = 1; off < 512; off <<= 1) {
        int t = (tid < 512 && tid >= off) ? s[tid - off] : 0;
        __syncthreads();
        if (tid < 512) s[tid] += t;
        __syncthreads();
    }
    if (tid < 512) h[tid] = es + s[tid] - v;   // row cursor
    if (tid < nr) rp[rbase + tid] = es + s[tid] - v;
    if (tid == 0 && rbase + nr == N) rp[N] = ee;
    __syncthreads();
    for (int i = es + tid; i < ee; i += blockDim.x) {
        int2 p = stageP[i];
        int pos = atomicAdd(&h[p.x >> 18], 1);
        int2 o;
        o.x = p.x & 0x3ffff;
        o.y = p.y;
        spair[pos] = o;
    }
}

// ---------------- SpMM (bf16 gather, one wave = one row, 2 edges/step) ----------------
// lane = half*32 + dp : half selects edge parity, dp selects dim pair (dims 2dp, 2dp+1)
// MODE 0: plain  — ob = pack(a)
// MODE 1: final  — out = 0.25*(emb + y1 + y2 + a); fp32 out split U/I, optional bf16 outIb
// MODE 2: norm   — yf = normalize(a)
// MODE 3: blend  — yf = 0.5*normalize(a) + 0.5*base
template <int MODE>
__global__ void k_spmm(const int* __restrict__ rp, const int2* __restrict__ sp,
                       const uint* __restrict__ xb,
                       const float* __restrict__ embA, const float* __restrict__ embB,
                       const uint* __restrict__ y1b, const uint* __restrict__ y2b,
                       float* __restrict__ outU, float* __restrict__ outI,
                       uint* __restrict__ outIb,
                       uint* __restrict__ ob, float* __restrict__ yf,
                       const float* __restrict__ base, int split, int nrows) {
    int r = blockIdx.x * (blockDim.x >> 6) + (threadIdx.x >> 6);
    if (r >= nrows) return;
    int lane = threadIdx.x & 63;
    int half = lane >> 5;
    int dp = lane & 31;

    int s0 = rp[r], e0 = rp[r + 1];
    float ax = 0.f, ay = 0.f;
    int i = s0;
    for (; i + 4 <= e0; i += 4) {
        int2 pa = sp[i + half];
        int2 pb = sp[i + 2 + half];
        uint wa = xb[(((long long)pa.x) << 5) + dp];
        uint wb = xb[(((long long)pb.x) << 5) + dp];
        float va = __int_as_float(pa.y);
        float vb = __int_as_float(pb.y);
        ax += va * bflo(wa); ay += va * bfhi(wa);
        ax += vb * bflo(wb); ay += vb * bfhi(wb);
    }
    for (; i < e0; i += 2) {
        int2 p;
        if (i + 1 < e0) p = sp[i + half];
        else if (half == 0) p = sp[i];
        else { p.x = 0; p.y = 0; }           // val=0 pad
        uint w = xb[(((long long)p.x) << 5) + dp];
        float v = __int_as_float(p.y);
        ax += v * bflo(w); ay += v * bfhi(w);
    }
    ax += __shfl_xor(ax, 32);
    ay += __shfl_xor(ay, 32);

    long long off2 = (((long long)r) << 6) + 2 * dp;

    if (MODE == 0) {
        if (half == 0) ob[(((long long)r) << 5) + dp] = pack_bf2(ax, ay);
    } else if (MODE == 1) {
        if (half == 0) {
            float2 e2;
            if (r < split) e2 = *(const float2*)(embA + off2);
            else           e2 = *(const float2*)(embB + (off2 - (((long long)split) << 6)));
            uint w1 = y1b[(((long long)r) << 5) + dp];
            uint w2 = y2b[(((long long)r) << 5) + dp];
            float sx = 0.25f * (e2.x + bflo(w1) + bflo(w2) + ax);
            float sy = 0.25f * (e2.y + bfhi(w1) + bfhi(w2) + ay);
            if (r < split) {
                float2 o; o.x = sx; o.y = sy;
                *(float2*)(outU + off2) = o;
            } else {
                long long o2 = off2 - (((long long)split) << 6);
                float2 o; o.x = sx; o.y = sy;
                *(float2*)(outI + o2) = o;
                if (outIb) outIb[(((long long)(r - split)) << 5) + dp] = pack_bf2(sx, sy);
            }
        }
    } else {
        float sq = ax * ax + ay * ay;
        for (int m = 16; m; m >>= 1) sq += __shfl_xor(sq, m);
        float inv = 1.0f / fmaxf(sqrtf(sq), 1e-12f);
        if (half == 0) {
            float2 o;
            if (MODE == 2) { o.x = ax * inv; o.y = ay * inv; }
            else {
                float2 b2 = *(const float2*)(base + off2);
                o.x = 0.5f * ax * inv + 0.5f * b2.x;
                o.y = 0.5f * ay * inv + 0.5f * b2.y;
            }
            *(float2*)(yf + off2) = o;
        }
    }
}

// ---------------- host ----------------

static inline int nblk(long long n, int b) { return (int)((n + b - 1) / b); }
static inline size_t al256(size_t x) { return (x + 255) & ~(size_t)255; }

extern "C" void kernel_launch(void* const* d_in, const int* in_sizes, int n_in,
                              void* d_out, int out_size, void* d_ws, size_t ws_size,
                              hipStream_t stream) {
    const float* emb_user   = (const float*)d_in[0];
    const float* emb_item   = (const float*)d_in[1];
    const float* emb_author = (const float*)d_in[2];
    const int*   g0r = (const int*)d_in[3];
    const int*   g0c = (const int*)d_in[4];
    const float* g0v = (const float*)d_in[5];
    const int*   g1r = (const int*)d_in[6];
    const int*   g1c = (const int*)d_in[7];
    const float* g1v = (const float*)d_in[8];
    const int*   g3r = (const int*)d_in[9];
    const int*   g3c = (const int*)d_in[10];
    const float* g3v = (const float*)d_in[11];
    const int*   g4r = (const int*)d_in[12];
    const int*   g4c = (const int*)d_in[13];
    const float* g4v = (const float*)d_in[14];
    const int*   g5r = (const int*)d_in[15];
    const int*   g5c = (const int*)d_in[16];
    const float* g5v = (const float*)d_in[17];

    const int E0 = in_sizes[3];
    const int E1 = in_sizes[6];
    const int E3 = in_sizes[9];
    const int E4 = in_sizes[12];
    const int E5 = in_sizes[15];

    float* out = (float*)d_out;

    // ---- workspace carve-up ----
    char* w = (char*)d_ws;
    int*  rp      = (int*)w;  w += al256((size_t)(NN0 + 1) * 4);
    int*  binCnt  = (int*)w;  w += al256((size_t)512 * 4);
    int*  binBase = (int*)w;  w += al256((size_t)513 * 4);
    int*  binCur  = (int*)w;  w += al256((size_t)512 * 4);
    int2* spair   = (int2*)w; w += al256((size_t)6400000 * 8);
    uint* xb0     = (uint*)w; w += al256((size_t)NN0 * 32 * 4);   // bf16 layer-0 input
    uint* y1b     = (uint*)w; w += al256((size_t)NN0 * 32 * 4);   // bf16 layer outs
    uint* y2b     = (uint*)w; w += al256((size_t)NN0 * 32 * 4);
    float* items0  = (float*)w; w += al256((size_t)NIi * DD * 4); // fp32 atom_items0
    uint*  items0b = (uint*)w;  w += al256((size_t)NIi * 32 * 4); // bf16 atom_items0
    uint*  oAuthNb = (uint*)w;  w += al256((size_t)NAa * 32 * 4); // bf16 non_atom_authors
    // staging aliases y1b+y2b (dead during builds): E*8 <= 51.2MB
    int2* stageP = (int2*)y1b;

    const int B = 256;

    auto build_csr = [&](const int* row, const int* col, const float* val,
                         int E, int N, int shift) {
        int nbins = (N + (1 << shift) - 1) >> shift;
        hipMemsetAsync(binCnt, 0, (size_t)nbins * sizeof(int), stream);
        k_binhist<<<nblk(E, 1024 * P1_ITER), 1024, 0, stream>>>(row, binCnt, E, shift, nbins);
        k_binscan<<<1, 512, 0, stream>>>(binCnt, binBase, binCur, nbins, E);
        k_part1<<<nblk(E, 1024 * P1_ITER), 1024, 0, stream>>>(row, col, val, binCur,
                                                              stageP, E, shift, nbins);
        k_part2<<<nbins, 1024, 0, stream>>>(binBase, stageP, spair, rp, N, shift);
    };

    float* oUserA = out;                            // atom_users
    float* oUserN = out + (long long)NUu * DD;      // non_atom_users
    float* oItemA = out + (long long)200000 * DD;   // atom_items
    float* oItemN = out + (long long)300000 * DD;   // non_atom_items
    float* oAuthA = out + (long long)400000 * DD;   // atom_authors
    float* oAuthN = out + (long long)410000 * DD;   // non_atom_authors

    // ========== atom branch: 3-layer propagate on g0 ==========
    build_csr(g0r, g0c, g0v, E0, NN0, 9);
    k_f2bf<<<nblk((long long)NUu * 16, B), B, 0, stream>>>((const float4*)emb_user,
                                                           (uint2*)xb0, NUu * 16);
    k_f2bf<<<nblk((long long)NIi * 16, B), B, 0, stream>>>((const float4*)emb_item,
                                                           (uint2*)(xb0 + (long long)NUu * 32),
                                                           NIi * 16);
    k_spmm<0><<<nblk(NN0, 4), B, 0, stream>>>(rp, spair, xb0, nullptr, nullptr, nullptr,
                                              nullptr, nullptr, nullptr, nullptr,
                                              y1b, nullptr, nullptr, NUu, NN0);
    k_spmm<0><<<nblk(NN0, 4), B, 0, stream>>>(rp, spair, y1b, nullptr, nullptr, nullptr,
                                              nullptr, nullptr, nullptr, nullptr,
                                              y2b, nullptr, nullptr, NUu, NN0);
    k_spmm<1><<<nblk(NN0, 4), B, 0, stream>>>(rp, spair, y2b, emb_user, emb_item,
                                              y1b, y2b, oUserA, items0, items0b,
                                              nullptr, nullptr, nullptr, NUu, NN0);

    // ========== non-atom branch: 3-layer propagate on g1 ==========
    build_csr(g1r, g1c, g1v, E1, NN1, 9);
    k_f2bf<<<nblk((long long)NUu * 16, B), B, 0, stream>>>((const float4*)emb_user,
                                                           (uint2*)xb0, NUu * 16);
    k_f2bf<<<nblk((long long)NAa * 16, B), B, 0, stream>>>((const float4*)emb_author,
                                                           (uint2*)(xb0 + (long long)NUu * 32),
                                                           NAa * 16);
    k_spmm<0><<<nblk(NN1, 4), B, 0, stream>>>(rp, spair, xb0, nullptr, nullptr, nullptr,
                                              nullptr, nullptr, nullptr, nullptr,
                                              y1b, nullptr, nullptr, NUu, NN1);
    k_spmm<0><<<nblk(NN1, 4), B, 0, stream>>>(rp, spair, y1b, nullptr, nullptr, nullptr,
                                              nullptr, nullptr, nullptr, nullptr,
                                              y2b, nullptr, nullptr, NUu, NN1);
    k_spmm<1><<<nblk(NN1, 4), B, 0, stream>>>(rp, spair, y2b, emb_user, emb_author,
                                              y1b, y2b, oUserN, oAuthN, oAuthNb,
                                              nullptr, nullptr, nullptr, NUu, NN1);

    // ========== atom_authors = normalize(g3 @ items0) ==========
    build_csr(g3r, g3c, g3v, E3, NAa, 5);
    k_spmm<2><<<nblk(NAa, 4), B, 0, stream>>>(rp, spair, items0b, nullptr, nullptr, nullptr,
                                              nullptr, nullptr, nullptr, nullptr,
                                              nullptr, oAuthA, nullptr, 0, NAa);

    // ========== atom_items = 0.5*normalize(g5 @ items0) + 0.5*items0 ==========
    build_csr(g5r, g5c, g5v, E5, NIi, 8);
    k_spmm<3><<<nblk(NIi, 4), B, 0, stream>>>(rp, spair, items0b, nullptr, nullptr, nullptr,
                                              nullptr, nullptr, nullptr, nullptr,
                                              nullptr, oItemA, items0, 0, NIi);

    // ========== non_atom_items = normalize(g4 @ non_atom_authors) ==========
    build_csr(g4r, g4c, g4v, E4, NIi, 8);
    k_spmm<2><<<nblk(NIi, 4), B, 0, stream>>>(rp, spair, oAuthNb, nullptr, nullptr, nullptr,
                                              nullptr, nullptr, nullptr, nullptr,
                                              nullptr, oItemN, nullptr, 0, NIi);
}